// Round 1
// baseline (383.282 us; speedup 1.0000x reference)
//
#include <hip/hip_runtime.h>
#include <hip/hip_bf16.h>

typedef __bf16 bf16x8 __attribute__((ext_vector_type(8)));
typedef float  f32x4  __attribute__((ext_vector_type(4)));

#define MFMA_16x16x32(a, b, c) __builtin_amdgcn_mfma_f32_16x16x32_bf16((a), (b), (c), 0, 0, 0)

static constexpr float SCALE  = 0.03125f;        // 1/sqrt(1024)
static constexpr float INV_NQ = 1.0f / 4096.0f;  // mean over 4S rows

__device__ inline bf16x8 ld_cvt_bf8(const float* __restrict__ p) {
    f32x4 x0 = *(const f32x4*)p;
    f32x4 x1 = *(const f32x4*)(p + 4);
    bf16x8 r;
    r[0] = (__bf16)x0[0]; r[1] = (__bf16)x0[1]; r[2] = (__bf16)x0[2]; r[3] = (__bf16)x0[3];
    r[4] = (__bf16)x1[0]; r[5] = (__bf16)x1[1]; r[6] = (__bf16)x1[2]; r[7] = (__bf16)x1[3];
    return r;
}

// ---- Kernel T: transpose 4 projection weights [1024,128] -> bf16 [128,1024] ----
__global__ __launch_bounds__(256) void kT(const float* __restrict__ Dq, const float* __restrict__ Vq,
                                          const float* __restrict__ Dk, const float* __restrict__ Vk,
                                          __bf16* __restrict__ Wt) {
    int idx = blockIdx.x * 256 + threadIdx.x;     // 4*131072 total
    int m   = idx >> 17;
    int rem = idx & 131071;
    int r   = rem >> 7;        // k in [0,1024)
    int c   = rem & 127;       // col in [0,128)
    const float* W = (m == 0) ? Dq : (m == 1) ? Vq : (m == 2) ? Dk : Vk;
    Wt[(size_t)m * 131072 + (size_t)c * 1024 + r] = (__bf16)W[rem];
}

// ---- Kernel P: q/k projections -> bf16 Q[b][4096][128], K[b][4096][128] ----
// grid: [qk(2)][row-tile(128)], block 256 = 4 waves, wave does 32 rows x 128 cols
__global__ __launch_bounds__(256) void kProj(
    const float* __restrict__ drums, const float* __restrict__ vocals,
    const float* __restrict__ bass,  const float* __restrict__ other,
    const float* __restrict__ Dqb, const float* __restrict__ Vqb,
    const float* __restrict__ Dkb, const float* __restrict__ Vkb,
    const __bf16* __restrict__ Wt, __bf16* __restrict__ Qb, __bf16* __restrict__ Kb) {
    int bx   = blockIdx.x;
    int qk   = bx >> 7;
    int tile = bx & 127;
    int grow0 = tile * 128;          // global row base in [0, 16384)
    int b    = grow0 >> 12;
    int r4   = grow0 & 4095;
    int stem = r4 >> 10;
    int rin  = r4 & 1023;

    const float* X = (stem == 0) ? drums : (stem == 1) ? vocals : (stem == 2) ? bass : other;
    const __bf16* W;
    const float* bias;
    if (qk == 0) { W = Wt + (size_t)((stem == 0) ? 0 : 1) * 131072; bias = (stem == 0) ? Dqb : Vqb; }
    else         { W = Wt + (size_t)((stem == 0) ? 2 : 3) * 131072; bias = (stem == 0) ? Dkb : Vkb; }
    __bf16* Out = (qk == 0) ? Qb : Kb;

    int lane = threadIdx.x & 63, wid = threadIdx.x >> 6;
    int l16 = lane & 15, g = lane >> 4;
    int wr = rin + wid * 32;         // wave row base within stem

    f32x4 acc[2][8];
#pragma unroll
    for (int i = 0; i < 2; i++)
#pragma unroll
        for (int j = 0; j < 8; j++) acc[i][j] = (f32x4){0.f, 0.f, 0.f, 0.f};

    const float* xr0 = X + ((size_t)b * 1024 + wr + l16) * 1024;
    const float* xr1 = xr0 + 16 * 1024;
    for (int k0 = 0; k0 < 1024; k0 += 32) {
        int ko = k0 + g * 8;
        bf16x8 a0 = ld_cvt_bf8(xr0 + ko);
        bf16x8 a1 = ld_cvt_bf8(xr1 + ko);
#pragma unroll
        for (int cf = 0; cf < 8; cf++) {
            bf16x8 bv = *(const bf16x8*)(W + (size_t)(cf * 16 + l16) * 1024 + ko);
            acc[0][cf] = MFMA_16x16x32(a0, bv, acc[0][cf]);
            acc[1][cf] = MFMA_16x16x32(a1, bv, acc[1][cf]);
        }
    }
    size_t obase = (size_t)b * 4096 + (size_t)stem * 1024;
#pragma unroll
    for (int rf = 0; rf < 2; rf++)
#pragma unroll
        for (int cf = 0; cf < 8; cf++) {
            int col = cf * 16 + l16;
            float bv = bias[col];
#pragma unroll
            for (int r = 0; r < 4; r++) {
                int row = wr + rf * 16 + g * 4 + r;
                Out[(obase + row) * 128 + col] = (__bf16)(acc[rf][cf][r] + bv);
            }
        }
}

// ---- Kernel S1: row sums l[q] = sum_k exp(s_qk) (no max; scores are tiny) ----
// grid 256: [b(4)][row-tile(32)][half(2)], block 4 waves, wave 32 rows; halves split the col stream
__global__ __launch_bounds__(256) void kRowSum(const __bf16* __restrict__ Qb,
                                               const __bf16* __restrict__ Kb,
                                               float* __restrict__ lsum) {
    int bx = blockIdx.x;
    int half = bx & 1;
    int rest = bx >> 1;
    int b = rest >> 5, tile = rest & 31;
    int lane = threadIdx.x & 63, wid = threadIdx.x >> 6;
    int l16 = lane & 15, g = lane >> 4;
    int R = tile * 128 + wid * 32;
    const __bf16* Qr = Qb + (size_t)b * 4096 * 128;
    const __bf16* Kr = Kb + (size_t)b * 4096 * 128;

    bf16x8 a[2][4];
#pragma unroll
    for (int rf = 0; rf < 2; rf++)
#pragma unroll
        for (int kf = 0; kf < 4; kf++)
            a[rf][kf] = *(const bf16x8*)(Qr + (size_t)(R + rf * 16 + l16) * 128 + kf * 32 + g * 8);

    float rs[2][4] = {};
    for (int ct = half * 128; ct < half * 128 + 128; ct++) {
        f32x4 acc0 = (f32x4){0.f, 0.f, 0.f, 0.f};
        f32x4 acc1 = (f32x4){0.f, 0.f, 0.f, 0.f};
#pragma unroll
        for (int kf = 0; kf < 4; kf++) {
            bf16x8 bv = *(const bf16x8*)(Kr + (size_t)(ct * 16 + l16) * 128 + kf * 32 + g * 8);
            acc0 = MFMA_16x16x32(a[0][kf], bv, acc0);
            acc1 = MFMA_16x16x32(a[1][kf], bv, acc1);
        }
#pragma unroll
        for (int r = 0; r < 4; r++) {
            rs[0][r] += __expf(acc0[r] * SCALE);
            rs[1][r] += __expf(acc1[r] * SCALE);
        }
    }
#pragma unroll
    for (int rf = 0; rf < 2; rf++)
#pragma unroll
        for (int r = 0; r < 4; r++) {
            float v = rs[rf][r];
#pragma unroll
            for (int m = 1; m < 16; m <<= 1) v += __shfl_xor(v, m);
            if (l16 == 0) atomicAdd(&lsum[(size_t)b * 4096 + R + rf * 16 + g * 4 + r], v);
        }
}

// ---- Kernel S2: col sums w[k] = sum_q exp(s_qk)/l_q ----
// grid 256: [b(4)][col-tile(32)][half(2)], wave 32 cols, streams Q rows
__global__ __launch_bounds__(256) void kColSum(const __bf16* __restrict__ Qb,
                                               const __bf16* __restrict__ Kb,
                                               const float* __restrict__ lsum,
                                               float* __restrict__ wsum) {
    __shared__ float linv[4096];
    int bx = blockIdx.x;
    int half = bx & 1;
    int rest = bx >> 1;
    int b = rest >> 5, tile = rest & 31;
    const float* lb = lsum + (size_t)b * 4096;
    for (int i = threadIdx.x; i < 4096; i += 256) linv[i] = 1.0f / lb[i];
    __syncthreads();

    int lane = threadIdx.x & 63, wid = threadIdx.x >> 6;
    int l16 = lane & 15, g = lane >> 4;
    int C = tile * 128 + wid * 32;
    const __bf16* Qr = Qb + (size_t)b * 4096 * 128;
    const __bf16* Kr = Kb + (size_t)b * 4096 * 128;

    bf16x8 kb[2][4];
#pragma unroll
    for (int cf = 0; cf < 2; cf++)
#pragma unroll
        for (int kf = 0; kf < 4; kf++)
            kb[cf][kf] = *(const bf16x8*)(Kr + (size_t)(C + cf * 16 + l16) * 128 + kf * 32 + g * 8);

    float cs[2] = {0.f, 0.f};
    for (int rt = half * 128; rt < half * 128 + 128; rt++) {
        f32x4 acc0 = (f32x4){0.f, 0.f, 0.f, 0.f};
        f32x4 acc1 = (f32x4){0.f, 0.f, 0.f, 0.f};
#pragma unroll
        for (int kf = 0; kf < 4; kf++) {
            bf16x8 av = *(const bf16x8*)(Qr + (size_t)(rt * 16 + l16) * 128 + kf * 32 + g * 8);
            acc0 = MFMA_16x16x32(av, kb[0][kf], acc0);
            acc1 = MFMA_16x16x32(av, kb[1][kf], acc1);
        }
#pragma unroll
        for (int r = 0; r < 4; r++) {
            float li = linv[rt * 16 + g * 4 + r];
            cs[0] += __expf(acc0[r] * SCALE) * li;
            cs[1] += __expf(acc1[r] * SCALE) * li;
        }
    }
#pragma unroll
    for (int cf = 0; cf < 2; cf++) {
        float v = cs[cf];
        v += __shfl_xor(v, 16);
        v += __shfl_xor(v, 32);
        if (lane < 16) atomicAdd(&wsum[(size_t)b * 4096 + C + cf * 16 + lane], v);
    }
}

// ---- Kernel Y: weighted stem sums (fp32) ----
// grid 128: [b(4)][stem(4)][kchunk(8)]; y[b][seg][1024], alpha[b][seg]
__global__ __launch_bounds__(256) void kY(
    const float* __restrict__ drums, const float* __restrict__ vocals,
    const float* __restrict__ bass,  const float* __restrict__ other,
    const float* __restrict__ wsum, float* __restrict__ y, float* __restrict__ alpha) {
    __shared__ float ws[128];
    int bx = blockIdx.x;
    int b = bx >> 5, stem = (bx >> 3) & 3, kc = bx & 7;
    const float* X = (stem == 0) ? drums : (stem == 1) ? vocals : (stem == 2) ? bass : other;
    int t = threadIdx.x;
    if (t < 128) ws[t] = wsum[(size_t)b * 4096 + stem * 1024 + kc * 128 + t] * INV_NQ;
    __syncthreads();

    f32x4 acc = (f32x4){0.f, 0.f, 0.f, 0.f};
    const float* xp = X + ((size_t)b * 1024 + kc * 128) * 1024 + t * 4;
    for (int i = 0; i < 128; i++) {
        f32x4 xv = *(const f32x4*)(xp + (size_t)i * 1024);
        float wv = ws[i];
        acc[0] += wv * xv[0]; acc[1] += wv * xv[1]; acc[2] += wv * xv[2]; acc[3] += wv * xv[3];
    }
    int seg = (stem == 0) ? 0 : 1;
    float* yp = y + ((size_t)b * 2 + seg) * 1024 + t * 4;
    atomicAdd(yp + 0, acc[0]); atomicAdd(yp + 1, acc[1]);
    atomicAdd(yp + 2, acc[2]); atomicAdd(yp + 3, acc[3]);

    if (t < 64) {
        float s = ws[t] + ws[t + 64];
#pragma unroll
        for (int m = 32; m > 0; m >>= 1) s += __shfl_down(s, m);
        if (t == 0) atomicAdd(alpha + b * 2 + seg, s);
    }
}

// ---- Kernel F: out[b][d] = yD@DvW + yV@VvW + aD*Dvb + aV*Vvb ----
// grid 64: [b(4)][dstripe(4)][kchunk(4)]
__global__ __launch_bounds__(256) void kFinal(
    const float* __restrict__ DvW, const float* __restrict__ Dvb,
    const float* __restrict__ VvW, const float* __restrict__ Vvb,
    const float* __restrict__ y, const float* __restrict__ alpha,
    float* __restrict__ out) {
    __shared__ float yD[256], yV[256];
    int bx = blockIdx.x;
    int b = bx >> 4, dstripe = (bx >> 2) & 3, kc = bx & 3;
    int t = threadIdx.x;
    yD[t] = y[((size_t)b * 2 + 0) * 1024 + kc * 256 + t];
    yV[t] = y[((size_t)b * 2 + 1) * 1024 + kc * 256 + t];
    __syncthreads();

    int d = dstripe * 256 + t;
    const float* pD = DvW + (size_t)(kc * 256) * 1024 + d;
    const float* pV = VvW + (size_t)(kc * 256) * 1024 + d;
    float acc = 0.f;
#pragma unroll 4
    for (int k = 0; k < 256; k++)
        acc += yD[k] * pD[(size_t)k * 1024] + yV[k] * pV[(size_t)k * 1024];
    if (kc == 0) acc += alpha[b * 2] * Dvb[d] + alpha[b * 2 + 1] * Vvb[d];
    atomicAdd(out + (size_t)b * 1024 + d, acc);
}

extern "C" void kernel_launch(void* const* d_in, const int* in_sizes, int n_in,
                              void* d_out, int out_size, void* d_ws, size_t ws_size,
                              hipStream_t stream) {
    const float* drums  = (const float*)d_in[0];
    const float* vocals = (const float*)d_in[1];
    const float* bass   = (const float*)d_in[2];
    const float* other  = (const float*)d_in[3];
    const float* DqW = (const float*)d_in[4];
    const float* Dqb = (const float*)d_in[5];
    const float* DkW = (const float*)d_in[6];
    const float* Dkb = (const float*)d_in[7];
    const float* DvW = (const float*)d_in[8];
    const float* Dvb = (const float*)d_in[9];
    const float* VqW = (const float*)d_in[10];
    const float* Vqb = (const float*)d_in[11];
    const float* VkW = (const float*)d_in[12];
    const float* Vkb = (const float*)d_in[13];
    const float* VvW = (const float*)d_in[14];
    const float* Vvb = (const float*)d_in[15];
    float* out = (float*)d_out;

    char* ws = (char*)d_ws;
    __bf16* Qb   = (__bf16*)(ws);                                  // 4 MB
    __bf16* Kb   = (__bf16*)(ws + (4u << 20));                     // 4 MB
    __bf16* Wt   = (__bf16*)(ws + (8u << 20));                     // 1 MB
    float*  lsum = (float*)(ws + (9u << 20));                      // 64 KB
    float*  wsum = (float*)(ws + (9u << 20) + (64u << 10));        // 64 KB
    float*  y    = (float*)(ws + (9u << 20) + (128u << 10));       // 32 KB
    float*  alph = (float*)(ws + (9u << 20) + (160u << 10));       // 32 B

    // zero l, w, y, alpha (contiguous) and out (accumulated via atomics)
    hipMemsetAsync(lsum, 0, (160u << 10) + 32, stream);
    hipMemsetAsync(out, 0, (size_t)out_size * sizeof(float), stream);

    kT<<<2048, 256, 0, stream>>>(DqW, VqW, DkW, VkW, Wt);
    kProj<<<256, 256, 0, stream>>>(drums, vocals, bass, other, Dqb, Vqb, Dkb, Vkb, Wt, Qb, Kb);
    kRowSum<<<256, 256, 0, stream>>>(Qb, Kb, lsum);
    kColSum<<<256, 256, 0, stream>>>(Qb, Kb, lsum, wsum);
    kY<<<128, 256, 0, stream>>>(drums, vocals, bass, other, wsum, y, alph);
    kFinal<<<64, 256, 0, stream>>>(DvW, Dvb, VvW, Vvb, y, alph, out);
}

// Round 3
// 329.687 us; speedup vs baseline: 1.1626x; 1.1626x over previous
//
#include <hip/hip_runtime.h>
#include <hip/hip_bf16.h>

typedef __bf16 bf16x8 __attribute__((ext_vector_type(8)));
typedef float  f32x4  __attribute__((ext_vector_type(4)));

#define MFMA(a, b, c) __builtin_amdgcn_mfma_f32_16x16x32_bf16((a), (b), (c), 0, 0, 0)

static constexpr float SC_L2E = 0.03125f * 1.44269504088896341f;  // (1/sqrt(1024)) * log2(e)
static constexpr float INV_NQ = 1.0f / 4096.0f;                   // mean over 4S rows

__device__ inline bf16x8 ld_cvt_bf8(const float* __restrict__ p) {
    f32x4 x0 = *(const f32x4*)p;
    f32x4 x1 = *(const f32x4*)(p + 4);
    bf16x8 r;
    r[0] = (__bf16)x0[0]; r[1] = (__bf16)x0[1]; r[2] = (__bf16)x0[2]; r[3] = (__bf16)x0[3];
    r[4] = (__bf16)x1[0]; r[5] = (__bf16)x1[1]; r[6] = (__bf16)x1[2]; r[7] = (__bf16)x1[3];
    return r;
}

// ---- Kernel T: transpose 4 projection weights [1024,128] -> bf16 [128,1024] ----
__global__ __launch_bounds__(256) void kT(const float* __restrict__ Dq, const float* __restrict__ Vq,
                                          const float* __restrict__ Dk, const float* __restrict__ Vk,
                                          __bf16* __restrict__ Wt) {
    int idx = blockIdx.x * 256 + threadIdx.x;     // 4*131072 total
    int m   = idx >> 17;
    int rem = idx & 131071;
    int r   = rem >> 7;        // k in [0,1024)
    int c   = rem & 127;       // col in [0,128)
    const float* W = (m == 0) ? Dq : (m == 1) ? Vq : (m == 2) ? Dk : Vk;
    Wt[(size_t)m * 131072 + (size_t)c * 1024 + r] = (__bf16)W[rem];
}

// ---- Kernel P: fused q+k projections -> bf16 Q[b][4096][128], K[b][4096][128] ----
// grid 256 blocks x 64 rows; block 256 = 4 waves, wave does 16 rows x (128 Q + 128 K cols).
// X read ONCE (67 MB HBM); weights stream from L1/L2.
__global__ __launch_bounds__(256) void kProj(
    const float* __restrict__ drums, const float* __restrict__ vocals,
    const float* __restrict__ bass,  const float* __restrict__ other,
    const float* __restrict__ Dqb, const float* __restrict__ Vqb,
    const float* __restrict__ Dkb, const float* __restrict__ Vkb,
    const __bf16* __restrict__ Wt, __bf16* __restrict__ Qb, __bf16* __restrict__ Kb) {
    int grow0 = blockIdx.x * 64;
    int b    = grow0 >> 12;
    int r4   = grow0 & 4095;
    int stem = r4 >> 10;
    int rin  = r4 & 1023;

    const float* X = (stem == 0) ? drums : (stem == 1) ? vocals : (stem == 2) ? bass : other;
    const __bf16* WQ = Wt + (size_t)((stem == 0) ? 0 : 1) * 131072;
    const __bf16* WK = Wt + (size_t)((stem == 0) ? 2 : 3) * 131072;
    const float* bQ = (stem == 0) ? Dqb : Vqb;
    const float* bK = (stem == 0) ? Dkb : Vkb;

    int lane = threadIdx.x & 63, wid = threadIdx.x >> 6;
    int l16 = lane & 15, g = lane >> 4;
    int wr = rin + wid * 16;         // wave row base within stem (16 rows)

    f32x4 aQ[8], aK[8];
#pragma unroll
    for (int j = 0; j < 8; j++) { aQ[j] = (f32x4){0.f,0.f,0.f,0.f}; aK[j] = (f32x4){0.f,0.f,0.f,0.f}; }

    const float* xr = X + ((size_t)b * 1024 + wr + l16) * 1024;
    for (int k0 = 0; k0 < 1024; k0 += 32) {
        int ko = k0 + g * 8;
        bf16x8 a = ld_cvt_bf8(xr + ko);
#pragma unroll
        for (int cf = 0; cf < 8; cf++) {
            bf16x8 wq = *(const bf16x8*)(WQ + (size_t)(cf * 16 + l16) * 1024 + ko);
            aQ[cf] = MFMA(a, wq, aQ[cf]);
            bf16x8 wk = *(const bf16x8*)(WK + (size_t)(cf * 16 + l16) * 1024 + ko);
            aK[cf] = MFMA(a, wk, aK[cf]);
        }
    }
    size_t obase = (size_t)b * 4096 + (size_t)stem * 1024;
#pragma unroll
    for (int cf = 0; cf < 8; cf++) {
        int col = cf * 16 + l16;
        float bvq = bQ[col], bvk = bK[col];
#pragma unroll
        for (int r = 0; r < 4; r++) {
            int row = wr + g * 4 + r;
            Qb[(obase + row) * 128 + col] = (__bf16)(aQ[cf][r] + bvq);
            Kb[(obase + row) * 128 + col] = (__bf16)(aK[cf][r] + bvk);
        }
    }
}

// ---- Kernel S1: row sums l[q] = sum_k exp(s_qk) ----
// grid 1024: [b(4)][rowtile(32)][colchunk(8)]; block 4 waves, wave 32 rows x 512-col stream.
// K tile (64 cols x 128) LDS-staged per block, XOR-swizzled ((row&7)<<4).
__global__ __launch_bounds__(256) void kRowSum(const __bf16* __restrict__ Qb,
                                               const __bf16* __restrict__ Kb,
                                               float* __restrict__ lsum) {
    __shared__ uint4 ktile[1024];    // 64 rows x 128 bf16 = 16 KB
    int bx = blockIdx.x;
    int cc = bx & 7, tile = (bx >> 3) & 31, b = bx >> 8;
    int lane = threadIdx.x & 63, wid = threadIdx.x >> 6;
    int l16 = lane & 15, g = lane >> 4;
    int R  = tile * 128 + wid * 32;
    int C0 = cc * 512;
    const __bf16* Qr = Qb + (size_t)b * 4096 * 128;
    const __bf16* Kr = Kb + (size_t)b * 4096 * 128;

    bf16x8 a[2][4];
#pragma unroll
    for (int rf = 0; rf < 2; rf++)
#pragma unroll
        for (int kf = 0; kf < 4; kf++)
            a[rf][kf] = *(const bf16x8*)(Qr + (size_t)(R + rf * 16 + l16) * 128 + kf * 32 + g * 8);

    int sr = threadIdx.x >> 2, sseg = threadIdx.x & 3;   // stage: row, 64B-segment
    char* kbc = (char*)ktile;
    int swm = (sr & 7) << 4;

    uint4 st[4];
    {
        const char* src = (const char*)(Kr + (size_t)(C0 + sr) * 128) + sseg * 64;
#pragma unroll
        for (int j = 0; j < 4; j++) st[j] = *(const uint4*)(src + j * 16);
    }

    float rs[2][4] = {};
    for (int s = 0; s < 8; ++s) {
        __syncthreads();
#pragma unroll
        for (int j = 0; j < 4; j++)
            *(uint4*)(kbc + sr * 256 + ((sseg * 64 + j * 16) ^ swm)) = st[j];
        __syncthreads();
        if (s < 7) {
            const char* src = (const char*)(Kr + (size_t)(C0 + (s + 1) * 64 + sr) * 128) + sseg * 64;
#pragma unroll
            for (int j = 0; j < 4; j++) st[j] = *(const uint4*)(src + j * 16);
        }
#pragma unroll
        for (int ctl = 0; ctl < 4; ++ctl) {
            int r2 = ctl * 16 + l16;
            int rm = (r2 & 7) << 4;
            f32x4 acc0 = (f32x4){0.f,0.f,0.f,0.f};
            f32x4 acc1 = (f32x4){0.f,0.f,0.f,0.f};
#pragma unroll
            for (int kf = 0; kf < 4; kf++) {
                bf16x8 bv = *(const bf16x8*)(kbc + r2 * 256 + ((kf * 64 + g * 16) ^ rm));
                acc0 = MFMA(a[0][kf], bv, acc0);
                acc1 = MFMA(a[1][kf], bv, acc1);
            }
#pragma unroll
            for (int r = 0; r < 4; r++) {
                rs[0][r] += exp2f(acc0[r] * SC_L2E);
                rs[1][r] += exp2f(acc1[r] * SC_L2E);
            }
        }
    }
#pragma unroll
    for (int rf = 0; rf < 2; rf++)
#pragma unroll
        for (int r = 0; r < 4; r++) {
            float v = rs[rf][r];
#pragma unroll
            for (int m = 1; m < 16; m <<= 1) v += __shfl_xor(v, m);
            if (l16 == 0) atomicAdd(&lsum[(size_t)b * 4096 + R + rf * 16 + g * 4 + r], v);
        }
}

// ---- Kernel I: linv = 1/lsum, 16384 elems ----
__global__ __launch_bounds__(256) void kInv(const float* __restrict__ lsum, float* __restrict__ linv) {
    int i = (blockIdx.x * 256 + threadIdx.x) * 4;
    f32x4 v = *(const f32x4*)(lsum + i);
    f32x4 r = (f32x4){1.f / v[0], 1.f / v[1], 1.f / v[2], 1.f / v[3]};
    *(f32x4*)(linv + i) = r;
}

// ---- Kernel S2: col sums w[k] = sum_q exp(s_qk)/l_q ----
// grid 1024: [b(4)][coltile(32)][rowchunk(8)]; wave 32 cols x 512-row stream; Q LDS-staged.
__global__ __launch_bounds__(256) void kColSum(const __bf16* __restrict__ Qb,
                                               const __bf16* __restrict__ Kb,
                                               const float* __restrict__ linv,
                                               float* __restrict__ wsum) {
    __shared__ uint4 qtile[1024];    // 64 rows x 128 bf16 = 16 KB
    __shared__ float li[512];
    int bx = blockIdx.x;
    int rc = bx & 7, tile = (bx >> 3) & 31, b = bx >> 8;
    int lane = threadIdx.x & 63, wid = threadIdx.x >> 6;
    int l16 = lane & 15, g = lane >> 4;
    int C  = tile * 128 + wid * 32;
    int R0 = rc * 512;
    const __bf16* Qr = Qb + (size_t)b * 4096 * 128;
    const __bf16* Kr = Kb + (size_t)b * 4096 * 128;

    if (threadIdx.x < 128)
        *(f32x4*)(li + threadIdx.x * 4) = *(const f32x4*)(linv + (size_t)b * 4096 + R0 + threadIdx.x * 4);

    bf16x8 kb[2][4];
#pragma unroll
    for (int cf = 0; cf < 2; cf++)
#pragma unroll
        for (int kf = 0; kf < 4; kf++)
            kb[cf][kf] = *(const bf16x8*)(Kr + (size_t)(C + cf * 16 + l16) * 128 + kf * 32 + g * 8);

    int sr = threadIdx.x >> 2, sseg = threadIdx.x & 3;
    char* qbc = (char*)qtile;
    int swm = (sr & 7) << 4;

    uint4 st[4];
    {
        const char* src = (const char*)(Qr + (size_t)(R0 + sr) * 128) + sseg * 64;
#pragma unroll
        for (int j = 0; j < 4; j++) st[j] = *(const uint4*)(src + j * 16);
    }

    float cs[2] = {0.f, 0.f};
    for (int s = 0; s < 8; ++s) {
        __syncthreads();
#pragma unroll
        for (int j = 0; j < 4; j++)
            *(uint4*)(qbc + sr * 256 + ((sseg * 64 + j * 16) ^ swm)) = st[j];
        __syncthreads();
        if (s < 7) {
            const char* src = (const char*)(Qr + (size_t)(R0 + (s + 1) * 64 + sr) * 128) + sseg * 64;
#pragma unroll
            for (int j = 0; j < 4; j++) st[j] = *(const uint4*)(src + j * 16);
        }
#pragma unroll
        for (int ctl = 0; ctl < 4; ++ctl) {
            int r2 = ctl * 16 + l16;
            int rm = (r2 & 7) << 4;
            f32x4 acc0 = (f32x4){0.f,0.f,0.f,0.f};
            f32x4 acc1 = (f32x4){0.f,0.f,0.f,0.f};
#pragma unroll
            for (int kf = 0; kf < 4; kf++) {
                bf16x8 av = *(const bf16x8*)(qbc + r2 * 256 + ((kf * 64 + g * 16) ^ rm));
                acc0 = MFMA(av, kb[0][kf], acc0);
                acc1 = MFMA(av, kb[1][kf], acc1);
            }
            int ib = s * 64 + ctl * 16 + g * 4;
#pragma unroll
            for (int r = 0; r < 4; r++) {
                float lv = li[ib + r];
                cs[0] += exp2f(acc0[r] * SC_L2E) * lv;
                cs[1] += exp2f(acc1[r] * SC_L2E) * lv;
            }
        }
    }
#pragma unroll
    for (int cf = 0; cf < 2; cf++) {
        float v = cs[cf];
        v += __shfl_xor(v, 16);
        v += __shfl_xor(v, 32);
        if (lane < 16) atomicAdd(&wsum[(size_t)b * 4096 + C + cf * 16 + lane], v);
    }
}

// ---- Kernel Y: weighted stem sums (fp32) ----
// grid 256: [b(4)][stem(4)][kchunk(16)] x 64 rows; y[b][seg][1024], alpha[b][seg]
__global__ __launch_bounds__(256) void kY(
    const float* __restrict__ drums, const float* __restrict__ vocals,
    const float* __restrict__ bass,  const float* __restrict__ other,
    const float* __restrict__ wsum, float* __restrict__ y, float* __restrict__ alpha) {
    __shared__ float ws[64];
    int bx = blockIdx.x;
    int b = bx >> 6, stem = (bx >> 4) & 3, kc = bx & 15;
    const float* X = (stem == 0) ? drums : (stem == 1) ? vocals : (stem == 2) ? bass : other;
    int t = threadIdx.x;
    if (t < 64) ws[t] = wsum[(size_t)b * 4096 + stem * 1024 + kc * 64 + t] * INV_NQ;
    __syncthreads();

    f32x4 acc = (f32x4){0.f, 0.f, 0.f, 0.f};
    const float* xp = X + ((size_t)b * 1024 + kc * 64) * 1024 + t * 4;
#pragma unroll 4
    for (int i = 0; i < 64; i++) {
        f32x4 xv = *(const f32x4*)(xp + (size_t)i * 1024);
        float wv = ws[i];
        acc[0] += wv * xv[0]; acc[1] += wv * xv[1]; acc[2] += wv * xv[2]; acc[3] += wv * xv[3];
    }
    int seg = (stem == 0) ? 0 : 1;
    float* yp = y + ((size_t)b * 2 + seg) * 1024 + t * 4;
    atomicAdd(yp + 0, acc[0]); atomicAdd(yp + 1, acc[1]);
    atomicAdd(yp + 2, acc[2]); atomicAdd(yp + 3, acc[3]);

    if (t < 64) {
        float s = ws[t];
#pragma unroll
        for (int m = 32; m > 0; m >>= 1) s += __shfl_down(s, m);
        if (t == 0) atomicAdd(alpha + b * 2 + seg, s);
    }
}

// ---- Kernel F: out[b][d] = yD@DvW + yV@VvW + aD*Dvb + aV*Vvb ----
// grid 128: [b(4)][dstripe(4)][kchunk(8)]
__global__ __launch_bounds__(256) void kFinal(
    const float* __restrict__ DvW, const float* __restrict__ Dvb,
    const float* __restrict__ VvW, const float* __restrict__ Vvb,
    const float* __restrict__ y, const float* __restrict__ alpha,
    float* __restrict__ out) {
    __shared__ float yD[128], yV[128];
    int bx = blockIdx.x;
    int b = bx >> 5, dstripe = (bx >> 3) & 3, kc = bx & 7;
    int t = threadIdx.x;
    if (t < 128) {
        yD[t] = y[((size_t)b * 2 + 0) * 1024 + kc * 128 + t];
        yV[t] = y[((size_t)b * 2 + 1) * 1024 + kc * 128 + t];
    }
    __syncthreads();

    int d = dstripe * 256 + t;
    const float* pD = DvW + (size_t)(kc * 128) * 1024 + d;
    const float* pV = VvW + (size_t)(kc * 128) * 1024 + d;
    float acc = 0.f;
#pragma unroll 4
    for (int k = 0; k < 128; k++)
        acc += yD[k] * pD[(size_t)k * 1024] + yV[k] * pV[(size_t)k * 1024];
    if (kc == 0) acc += alpha[b * 2] * Dvb[d] + alpha[b * 2 + 1] * Vvb[d];
    atomicAdd(out + (size_t)b * 1024 + d, acc);
}

extern "C" void kernel_launch(void* const* d_in, const int* in_sizes, int n_in,
                              void* d_out, int out_size, void* d_ws, size_t ws_size,
                              hipStream_t stream) {
    const float* drums  = (const float*)d_in[0];
    const float* vocals = (const float*)d_in[1];
    const float* bass   = (const float*)d_in[2];
    const float* other  = (const float*)d_in[3];
    const float* DqW = (const float*)d_in[4];
    const float* Dqb = (const float*)d_in[5];
    const float* DkW = (const float*)d_in[6];
    const float* Dkb = (const float*)d_in[7];
    const float* DvW = (const float*)d_in[8];
    const float* Dvb = (const float*)d_in[9];
    const float* VqW = (const float*)d_in[10];
    const float* Vqb = (const float*)d_in[11];
    const float* VkW = (const float*)d_in[12];
    const float* Vkb = (const float*)d_in[13];
    const float* VvW = (const float*)d_in[14];
    const float* Vvb = (const float*)d_in[15];
    float* out = (float*)d_out;

    char* ws = (char*)d_ws;
    __bf16* Qb   = (__bf16*)(ws);                                  // 4 MB
    __bf16* Kb   = (__bf16*)(ws + (4u << 20));                     // 4 MB
    __bf16* Wt   = (__bf16*)(ws + (8u << 20));                     // 1 MB
    float*  lsum = (float*)(ws + (9u << 20));                      // 64 KB
    float*  wsum = (float*)(ws + (9u << 20) + (64u << 10));        // 64 KB
    float*  y    = (float*)(ws + (9u << 20) + (128u << 10));       // 32 KB
    float*  alph = (float*)(ws + (9u << 20) + (160u << 10));       // 32 B
    float*  linv = (float*)(ws + (9u << 20) + (192u << 10));       // 64 KB

    // zero lsum/wsum/y/alpha (contiguous) and out (accumulated via atomics)
    hipMemsetAsync(lsum, 0, (160u << 10) + 32, stream);
    hipMemsetAsync(out, 0, (size_t)out_size * sizeof(float), stream);

    kT<<<2048, 256, 0, stream>>>(DqW, VqW, DkW, VkW, Wt);
    kProj<<<256, 256, 0, stream>>>(drums, vocals, bass, other, Dqb, Vqb, Dkb, Vkb, Wt, Qb, Kb);
    kRowSum<<<1024, 256, 0, stream>>>(Qb, Kb, lsum);
    kInv<<<16, 256, 0, stream>>>(lsum, linv);
    kColSum<<<1024, 256, 0, stream>>>(Qb, Kb, linv, wsum);
    kY<<<256, 256, 0, stream>>>(drums, vocals, bass, other, wsum, y, alph);
    kFinal<<<128, 256, 0, stream>>>(DvW, Dvb, VvW, Vvb, y, alph, out);
}